// Round 7
// baseline (141.829 us; speedup 1.0000x reference)
//
#include <hip/hip_runtime.h>

// RNN: h_s = tanh(X[s,b]*W_ih + b_ih + b_hh + W_hh @ h_{s-1}); y_s = W_out·h_s + b_out
// S=512, B=4096, HID=30.
// LDS-free systolic layout (R4/R6 were DS-pipe-throughput-bound: one DS unit
// per CU, ~512 cy/CU/step of broadcast reads):
//   16 lanes per batch element, 4 elements per 64-lane wave (rows of 16).
//   Lane r owns units {r, r+16}; unit 30 = W_out row (acc == y), 31 = pad.
//   k-broadcast via mov_dpp row_ror:t (VALU pipe, per-SIMD, no LDS, no chain:
//   each rotation is a single hop from the original h register).
//   Weights pre-permuted per lane so all register indices are static.
// 1024 waves, 1/SIMD: loop is VALU-issue-bound with a ~110 cy chain.

#define SEQ 512
#define BATCH 4096
#define HID 30

__device__ __forceinline__ float tanh_fast(float t) {
  const float c = __builtin_amdgcn_fmed3f(t, -9.f, 9.f);
  const float e = __builtin_amdgcn_exp2f(c * 2.885390081777927f);  // 2*log2(e)
  return fmaf(-2.f, __builtin_amdgcn_rcpf(e + 1.f), 1.f);
}

__global__ __launch_bounds__(256, 1) void rnn_tanh_kernel(
    const float* __restrict__ X,      // [SEQ, BATCH]
    const float* __restrict__ W_ih,   // [HID, 1]
    const float* __restrict__ W_hh,   // [HID, HID]
    const float* __restrict__ b_ih,   // [HID]
    const float* __restrict__ b_hh,   // [HID]
    const float* __restrict__ W_out,  // [1, HID]
    const float* __restrict__ b_out,  // [1]
    float* __restrict__ Y)            // [SEQ, BATCH]
{
  const int tid  = threadIdx.x;
  const int lane = tid & 63;
  const int r    = lane & 15;                  // lane within 16-lane row
  const int hiu  = r + 16;                     // high unit (30 = y-row, 31 = pad)
  const int elem = blockIdx.x * 16 + (tid >> 4);  // batch element (per 16-lane row)
  const bool is14 = (r == 14);                 // owner of unit 30 (y)

  // Pre-permuted weights: at rotation t, this lane receives h_{(r-t)&15} (lo)
  // and h_{16+((r-t)&15)} (hi) via row_ror:t. Columns >= 30 are zero (pad h).
  float wa[16], wb[16], wc[16], wd[16];
#pragma unroll
  for (int t = 0; t < 16; ++t) {
    const int cA = (r - t) & 15;   // lo-k column (always < 30)
    const int cB = cA + 16;        // hi-k column (30,31 -> zero)
    wa[t] = W_hh[r * HID + cA];
    wb[t] = (cB < HID) ? W_hh[r * HID + cB] : 0.f;
    wc[t] = (hiu < HID) ? W_hh[hiu * HID + cA]
                        : (hiu == HID ? W_out[cA] : 0.f);
    wd[t] = (cB < HID) ? ((hiu < HID) ? W_hh[hiu * HID + cB]
                                      : (hiu == HID ? W_out[cB] : 0.f))
                       : 0.f;
  }
  float wihLo = W_ih[r];
  float bLo   = b_ih[r] + b_hh[r];
  float wihHi = (hiu < HID) ? W_ih[hiu] : 0.f;
  float bHi   = (hiu < HID) ? (b_ih[hiu] + b_hh[hiu])
                            : (hiu == HID ? b_out[0] : 0.f);

  // Pin loop-invariant weights into arch VGPRs (R3 lesson).
#pragma unroll
  for (int t = 0; t < 16; ++t) {
    asm volatile("" : "+v"(wa[t]), "+v"(wb[t]), "+v"(wc[t]), "+v"(wd[t]));
  }
  asm volatile("" : "+v"(wihLo), "+v"(bLo), "+v"(wihHi), "+v"(bHi));

  float hA = 0.f, hB = 0.f;  // h[r], h[r+16]

  // Depth-8 rotating X prefetch (covers HBM/L2 latency at 1 wave/SIMD).
  const float* Xg = X + elem;
  float x0 = Xg[0 * BATCH], x1 = Xg[1 * BATCH], x2 = Xg[2 * BATCH],
        x3 = Xg[3 * BATCH], x4 = Xg[4 * BATCH], x5 = Xg[5 * BATCH],
        x6 = Xg[6 * BATCH], x7 = Xg[7 * BATCH];

  // One k-rotation: single-hop row_ror:T from the ORIGINAL h registers.
#define KROT(T)                                                              \
  {                                                                          \
    const float ra = __int_as_float(__builtin_amdgcn_mov_dpp(                \
        __float_as_int(hA), 0x120 + T, 0xf, 0xf, false));                    \
    const float rb = __int_as_float(__builtin_amdgcn_mov_dpp(                \
        __float_as_int(hB), 0x120 + T, 0xf, 0xf, false));                    \
    a0 = fmaf(wa[T], ra, a0);                                                \
    b0 = fmaf(wc[T], ra, b0);                                                \
    a1 = fmaf(wb[T], rb, a1);                                                \
    b1 = fmaf(wd[T], rb, b1);                                                \
  }

  auto STEP = [&](int s, float& xreg) {
    float a0 = fmaf(xreg, wihLo, bLo);
    float b0 = fmaf(xreg, wihHi, bHi);
    const int snext = (s + 8 < SEQ) ? s + 8 : SEQ - 1;
    xreg = Xg[snext * BATCH];

    // t = 0: own h values, no rotation.
    float a1 = wb[0] * hB;
    float b1 = wd[0] * hB;
    a0 = fmaf(wa[0], hA, a0);
    b0 = fmaf(wc[0], hA, b0);
    KROT(1)  KROT(2)  KROT(3)  KROT(4)  KROT(5)
    KROT(6)  KROT(7)  KROT(8)  KROT(9)  KROT(10)
    KROT(11) KROT(12) KROT(13) KROT(14) KROT(15)

    const float accA = a0 + a1;
    const float accB = b0 + b1;

    // Lane r=14: accB is unit 30 = y_{s-1} = W_out·h_{s-1} + b_out.
    if (s != 0 && is14) Y[(s - 1) * BATCH + elem] = accB;

    hA = tanh_fast(accA);
    hB = tanh_fast(accB);  // lane14/15's hB never consumed (cols 30,31 zeroed)
  };

  for (int s = 0; s < SEQ; s += 8) {
    STEP(s + 0, x0);
    STEP(s + 1, x1);
    STEP(s + 2, x2);
    STEP(s + 3, x3);
    STEP(s + 4, x4);
    STEP(s + 5, x5);
    STEP(s + 6, x6);
    STEP(s + 7, x7);
  }

  // Epilogue: y_{SEQ-1} from h_{SEQ-1} (only the hi/y chain needed).
  {
    float b0 = fmaf(wc[0], hA, bHi);
    float b1 = wd[0] * hB;
    float a0 = 0.f, a1 = 0.f;
    (void)a0; (void)a1;
#define KROTY(T)                                                             \
    {                                                                        \
      const float ra = __int_as_float(__builtin_amdgcn_mov_dpp(              \
          __float_as_int(hA), 0x120 + T, 0xf, 0xf, false));                  \
      const float rb = __int_as_float(__builtin_amdgcn_mov_dpp(              \
          __float_as_int(hB), 0x120 + T, 0xf, 0xf, false));                  \
      b0 = fmaf(wc[T], ra, b0);                                              \
      b1 = fmaf(wd[T], rb, b1);                                              \
    }
    KROTY(1)  KROTY(2)  KROTY(3)  KROTY(4)  KROTY(5)
    KROTY(6)  KROTY(7)  KROTY(8)  KROTY(9)  KROTY(10)
    KROTY(11) KROTY(12) KROTY(13) KROTY(14) KROTY(15)
    if (is14) Y[(SEQ - 1) * BATCH + elem] = b0 + b1;
  }
}

extern "C" void kernel_launch(void* const* d_in, const int* in_sizes, int n_in,
                              void* d_out, int out_size, void* d_ws, size_t ws_size,
                              hipStream_t stream) {
  const float* X     = (const float*)d_in[0];
  const float* W_ih  = (const float*)d_in[1];
  const float* W_hh  = (const float*)d_in[2];
  const float* b_ih  = (const float*)d_in[3];
  const float* b_hh  = (const float*)d_in[4];
  const float* W_out = (const float*)d_in[5];
  const float* b_out = (const float*)d_in[6];
  float* Y = (float*)d_out;

  // 16 lanes per element: 256 blocks x 256 threads = 1024 waves, 1/SIMD.
  dim3 grid(BATCH / 16), block(256);
  rnn_tanh_kernel<<<grid, block, 0, stream>>>(X, W_ih, W_hh, b_ih, b_hh,
                                              W_out, b_out, Y);
}

// Round 8
// 140.255 us; speedup vs baseline: 1.0112x; 1.0112x over previous
//
#include <hip/hip_runtime.h>

// RNN: h_s = tanh(X[s,b]*W_ih + b_ih + b_hh + W_hh @ h_{s-1}); y_s = W_out·h_s + b_out
// S=512, B=4096, HID=30.
// 16-lane systolic, LDS-free (R4/R6 were DS-pipe-bound). Lane r owns units
// {r, r+16} (30 = W_out row -> acc == y, 31 = pad). k-broadcast via
// mov_dpp row_ror:t (VALU). Weights pre-permuted per lane.
// R7 lesson: VGPR_Count=60 < 64 weights -> allocator spilled the "pinned"
// weights to scratch (L2-resident, invisible in FETCH, ~64 reloads/step).
// Fix: re-pin INSIDE the loop (once per 8-step group) + waves_per_eu(1,1)
// so spilling has no payoff and the budget is the full 512 VGPRs.

#define SEQ 512
#define BATCH 4096
#define HID 30

__device__ __forceinline__ float tanh_fast(float t) {
  const float c = __builtin_amdgcn_fmed3f(t, -9.f, 9.f);
  const float e = __builtin_amdgcn_exp2f(c * 2.885390081777927f);  // 2*log2(e)
  return fmaf(-2.f, __builtin_amdgcn_rcpf(e + 1.f), 1.f);
}

__global__ __attribute__((amdgpu_flat_work_group_size(256, 256),
                          amdgpu_waves_per_eu(1, 1)))
void rnn_tanh_kernel(
    const float* __restrict__ X,      // [SEQ, BATCH]
    const float* __restrict__ W_ih,   // [HID, 1]
    const float* __restrict__ W_hh,   // [HID, HID]
    const float* __restrict__ b_ih,   // [HID]
    const float* __restrict__ b_hh,   // [HID]
    const float* __restrict__ W_out,  // [1, HID]
    const float* __restrict__ b_out,  // [1]
    float* __restrict__ Y)            // [SEQ, BATCH]
{
  const int tid  = threadIdx.x;
  const int r    = tid & 15;                      // lane within 16-lane row
  const int hiu  = r + 16;                        // high unit (30 = y-row, 31 = pad)
  const int elem = blockIdx.x * 16 + (tid >> 4);  // batch element per 16-lane row
  const bool is14 = (r == 14);                    // owner of unit 30 (y)

  // Pre-permuted weights: at rotation t this lane receives h_{(r-t)&15} (lo)
  // and h_{16+((r-t)&15)} (hi) via row_ror:t. Columns >= 30 are zero.
  float wa[16], wb[16], wc[16], wd[16];
#pragma unroll
  for (int t = 0; t < 16; ++t) {
    const int cA = (r - t) & 15;   // lo-k column (< 30 always)
    const int cB = cA + 16;        // hi-k column (30,31 -> zero)
    wa[t] = W_hh[r * HID + cA];
    wb[t] = (cB < HID) ? W_hh[r * HID + cB] : 0.f;
    wc[t] = (hiu < HID) ? W_hh[hiu * HID + cA]
                        : (hiu == HID ? W_out[cA] : 0.f);
    wd[t] = (cB < HID) ? ((hiu < HID) ? W_hh[hiu * HID + cB]
                                      : (hiu == HID ? W_out[cB] : 0.f))
                       : 0.f;
  }
  float wihLo = W_ih[r];
  float bLo   = b_ih[r] + b_hh[r];
  float wihHi = (hiu < HID) ? W_ih[hiu] : 0.f;
  float bHi   = (hiu < HID) ? (b_ih[hiu] + b_hh[hiu])
                            : (hiu == HID ? b_out[0] : 0.f);

  float hA = 0.f, hB = 0.f;  // h[r], h[r+16]

  // Depth-8 rotating X prefetch.
  const float* Xg = X + elem;
  float x0 = Xg[0 * BATCH], x1 = Xg[1 * BATCH], x2 = Xg[2 * BATCH],
        x3 = Xg[3 * BATCH], x4 = Xg[4 * BATCH], x5 = Xg[5 * BATCH],
        x6 = Xg[6 * BATCH], x7 = Xg[7 * BATCH];

  // Zero-cost residency pins for all loop-invariants.
#define PIN_ALL()                                                            \
  {                                                                          \
    _Pragma("unroll")                                                        \
    for (int t = 0; t < 16; ++t) {                                           \
      asm volatile("" : "+v"(wa[t]), "+v"(wb[t]), "+v"(wc[t]), "+v"(wd[t])); \
    }                                                                        \
    asm volatile("" : "+v"(wihLo), "+v"(bLo), "+v"(wihHi), "+v"(bHi));       \
  }

  PIN_ALL()

#define KROT(T)                                                              \
  {                                                                          \
    const float ra = __int_as_float(__builtin_amdgcn_mov_dpp(                \
        __float_as_int(hA), 0x120 + T, 0xf, 0xf, false));                    \
    const float rb = __int_as_float(__builtin_amdgcn_mov_dpp(                \
        __float_as_int(hB), 0x120 + T, 0xf, 0xf, false));                    \
    a0 = fmaf(wa[T], ra, a0);                                                \
    b0 = fmaf(wc[T], ra, b0);                                                \
    a1 = fmaf(wb[T], rb, a1);                                                \
    b1 = fmaf(wd[T], rb, b1);                                                \
  }

  auto STEP = [&](int s, float& xreg) {
    float a0 = fmaf(xreg, wihLo, bLo);
    float b0 = fmaf(xreg, wihHi, bHi);
    const int snext = (s + 8 < SEQ) ? s + 8 : SEQ - 1;
    xreg = Xg[snext * BATCH];

    float a1 = wb[0] * hB;
    float b1 = wd[0] * hB;
    a0 = fmaf(wa[0], hA, a0);
    b0 = fmaf(wc[0], hA, b0);
    KROT(1)  KROT(2)  KROT(3)  KROT(4)  KROT(5)
    KROT(6)  KROT(7)  KROT(8)  KROT(9)  KROT(10)
    KROT(11) KROT(12) KROT(13) KROT(14) KROT(15)

    const float accA = a0 + a1;
    const float accB = b0 + b1;

    // Lane r=14: accB is unit 30 = y_{s-1} = W_out·h_{s-1} + b_out.
    if (s != 0 && is14) Y[(s - 1) * BATCH + elem] = accB;

    hA = tanh_fast(accA);
    hB = tanh_fast(accB);
  };

  for (int s = 0; s < SEQ; s += 8) {
    PIN_ALL()   // re-pin every 8 steps: spilling has no payoff anywhere
    STEP(s + 0, x0);
    STEP(s + 1, x1);
    STEP(s + 2, x2);
    STEP(s + 3, x3);
    STEP(s + 4, x4);
    STEP(s + 5, x5);
    STEP(s + 6, x6);
    STEP(s + 7, x7);
  }

  // Epilogue: y_{SEQ-1} from h_{SEQ-1} (hi/y chain only).
  {
    float b0 = fmaf(wc[0], hA, bHi);
    float b1 = wd[0] * hB;
#define KROTY(T)                                                             \
    {                                                                        \
      const float ra = __int_as_float(__builtin_amdgcn_mov_dpp(              \
          __float_as_int(hA), 0x120 + T, 0xf, 0xf, false));                  \
      const float rb = __int_as_float(__builtin_amdgcn_mov_dpp(              \
          __float_as_int(hB), 0x120 + T, 0xf, 0xf, false));                  \
      b0 = fmaf(wc[T], ra, b0);                                              \
      b1 = fmaf(wd[T], rb, b1);                                              \
    }
    KROTY(1)  KROTY(2)  KROTY(3)  KROTY(4)  KROTY(5)
    KROTY(6)  KROTY(7)  KROTY(8)  KROTY(9)  KROTY(10)
    KROTY(11) KROTY(12) KROTY(13) KROTY(14) KROTY(15)
    if (is14) Y[(SEQ - 1) * BATCH + elem] = b0 + b1;
  }
}

extern "C" void kernel_launch(void* const* d_in, const int* in_sizes, int n_in,
                              void* d_out, int out_size, void* d_ws, size_t ws_size,
                              hipStream_t stream) {
  const float* X     = (const float*)d_in[0];
  const float* W_ih  = (const float*)d_in[1];
  const float* W_hh  = (const float*)d_in[2];
  const float* b_ih  = (const float*)d_in[3];
  const float* b_hh  = (const float*)d_in[4];
  const float* W_out = (const float*)d_in[5];
  const float* b_out = (const float*)d_in[6];
  float* Y = (float*)d_out;

  // 16 lanes/elem: 256 blocks x 256 threads = 1024 waves = 1 per SIMD,
  // exactly 1 block per CU.
  dim3 grid(BATCH / 16), block(256);
  rnn_tanh_kernel<<<grid, block, 0, stream>>>(X, W_ih, W_hh, b_ih, b_hh,
                                              W_out, b_out, Y);
}

// Round 9
// 138.157 us; speedup vs baseline: 1.0266x; 1.0152x over previous
//
#include <hip/hip_runtime.h>

// RNN: h_s = tanh(X[s,b]*W_ih + b_ih + b_hh + W_hh @ h_{s-1}); y_s = W_out·h_s + b_out
// S=512, B=4096, HID=30.
// 16-lane systolic, LDS-free recurrence (R4/R6: DS-broadcast of h saturates the
// DS pipe). Lane r owns units {r, r+16} (30 = W_out row -> acc == y, 31 = pad).
// k-broadcast via mov_dpp row_ror:t. Weights pre-permuted per lane, pinned in
// VGPRs (R8: VGPR_Count=132 confirms residency).
// R9 change: X is staged block-wide into LDS up front (16 elems x 512 steps =
// 32 KB, coalesced float4), so the step loop has ZERO global loads -> no vmcnt
// waits can land on the recurrence (R2-R8 plateau ~690 cy/step ≈ HBM latency
// scale; loads+stores share vmcnt on CDNA). In-loop X = broadcast ds_read_b32
// prefetched 8 steps ahead (in-order lgkm queue).

#define SEQ 512
#define BATCH 4096
#define HID 30

__device__ __forceinline__ float tanh_fast(float t) {
  const float c = __builtin_amdgcn_fmed3f(t, -9.f, 9.f);
  const float e = __builtin_amdgcn_exp2f(c * 2.885390081777927f);  // 2*log2(e)
  return fmaf(-2.f, __builtin_amdgcn_rcpf(e + 1.f), 1.f);
}

__global__ __attribute__((amdgpu_flat_work_group_size(256, 256),
                          amdgpu_waves_per_eu(1, 1)))
void rnn_tanh_kernel(
    const float* __restrict__ X,      // [SEQ, BATCH]
    const float* __restrict__ W_ih,   // [HID, 1]
    const float* __restrict__ W_hh,   // [HID, HID]
    const float* __restrict__ b_ih,   // [HID]
    const float* __restrict__ b_hh,   // [HID]
    const float* __restrict__ W_out,  // [1, HID]
    const float* __restrict__ b_out,  // [1]
    float* __restrict__ Y)            // [SEQ, BATCH]
{
  const int tid  = threadIdx.x;
  const int r    = tid & 15;             // lane within 16-lane row
  const int hiu  = r + 16;               // high unit (30 = y-row, 31 = pad)
  const int row  = tid >> 4;             // elem index within block (0..15)
  const int e0   = blockIdx.x * 16;
  const int elem = e0 + row;
  const bool is14 = (r == 14);           // owner of unit 30 (y)

  __shared__ float xs[SEQ * 16];         // 32 KB: X[s][elem-in-block]

  // ---- Stage X for this block's 16 elems (coalesced float4) ----
  {
    const int c4 = (tid & 3) * 4;        // float column within the 16-elem row
    const int sr = tid >> 2;             // s-row, stride 64
#pragma unroll
    for (int it = 0; it < 8; ++it) {
      const int s = sr + 64 * it;
      const float4 v =
          *reinterpret_cast<const float4*>(X + (size_t)s * BATCH + e0 + c4);
      *reinterpret_cast<float4*>(&xs[s * 16 + c4]) = v;
    }
  }

  // ---- Per-lane weights: at rotation t this lane receives h_{(r-t)&15} (lo)
  // and h_{16+((r-t)&15)} (hi) via row_ror:t. Columns >= 30 are zero. ----
  float wa[16], wb[16], wc[16], wd[16];
#pragma unroll
  for (int t = 0; t < 16; ++t) {
    const int cA = (r - t) & 15;   // lo-k column (< 30 always)
    const int cB = cA + 16;        // hi-k column (30,31 -> zero)
    wa[t] = W_hh[r * HID + cA];
    wb[t] = (cB < HID) ? W_hh[r * HID + cB] : 0.f;
    wc[t] = (hiu < HID) ? W_hh[hiu * HID + cA]
                        : (hiu == HID ? W_out[cA] : 0.f);
    wd[t] = (cB < HID) ? ((hiu < HID) ? W_hh[hiu * HID + cB]
                                      : (hiu == HID ? W_out[cB] : 0.f))
                       : 0.f;
  }
  float wihLo = W_ih[r];
  float bLo   = b_ih[r] + b_hh[r];
  float wihHi = (hiu < HID) ? W_ih[hiu] : 0.f;
  float bHi   = (hiu < HID) ? (b_ih[hiu] + b_hh[hiu])
                            : (hiu == HID ? b_out[0] : 0.f);

  __syncthreads();                       // X staged

  float hA = 0.f, hB = 0.f;              // h[r], h[r+16]

  // Depth-8 X prefetch from LDS (in-order lgkm; read issued 8 steps ahead).
  const float* xp = &xs[row];
  float x0 = xp[0 * 16], x1 = xp[1 * 16], x2 = xp[2 * 16], x3 = xp[3 * 16],
        x4 = xp[4 * 16], x5 = xp[5 * 16], x6 = xp[6 * 16], x7 = xp[7 * 16];

  // Zero-cost residency pins for all loop-invariants (R7/R8 lesson).
#define PIN_ALL()                                                            \
  {                                                                          \
    _Pragma("unroll")                                                        \
    for (int t = 0; t < 16; ++t) {                                           \
      asm volatile("" : "+v"(wa[t]), "+v"(wb[t]), "+v"(wc[t]), "+v"(wd[t])); \
    }                                                                        \
    asm volatile("" : "+v"(wihLo), "+v"(bLo), "+v"(wihHi), "+v"(bHi));       \
  }

  PIN_ALL()

  // One k-rotation: single-hop row_ror:T from the ORIGINAL h registers.
  // Chains split 8-deep: wa -> a0/a2, wb -> a1/a3, wc -> b0/b2, wd -> b1/b3.
#define KROT(T)                                                              \
  {                                                                          \
    const float ra = __int_as_float(__builtin_amdgcn_mov_dpp(                \
        __float_as_int(hA), 0x120 + T, 0xf, 0xf, false));                    \
    const float rb = __int_as_float(__builtin_amdgcn_mov_dpp(                \
        __float_as_int(hB), 0x120 + T, 0xf, 0xf, false));                    \
    if (T < 8) {                                                             \
      a0 = fmaf(wa[T], ra, a0); b0 = fmaf(wc[T], ra, b0);                    \
      a1 = fmaf(wb[T], rb, a1); b1 = fmaf(wd[T], rb, b1);                    \
    } else {                                                                 \
      a2 = fmaf(wa[T], ra, a2); b2 = fmaf(wc[T], ra, b2);                    \
      a3 = fmaf(wb[T], rb, a3); b3 = fmaf(wd[T], rb, b3);                    \
    }                                                                        \
  }

  auto STEP = [&](int s, float& xreg) {
    float a0 = fmaf(xreg, wihLo, bLo);
    float b0 = fmaf(xreg, wihHi, bHi);
    const int snext = (s + 8 < SEQ) ? s + 8 : SEQ - 1;
    xreg = xp[snext * 16];               // broadcast ds_read_b32

    float a1 = wb[0] * hB;
    float b1 = wd[0] * hB;
    float a2 = 0.f, a3 = 0.f, b2 = 0.f, b3 = 0.f;
    a0 = fmaf(wa[0], hA, a0);
    b0 = fmaf(wc[0], hA, b0);
    KROT(1)  KROT(2)  KROT(3)  KROT(4)  KROT(5)
    KROT(6)  KROT(7)  KROT(8)  KROT(9)  KROT(10)
    KROT(11) KROT(12) KROT(13) KROT(14) KROT(15)

    const float accA = (a0 + a2) + (a1 + a3);
    const float accB = (b0 + b2) + (b1 + b3);

    // Lane r=14: accB is unit 30 = y_{s-1} = W_out·h_{s-1} + b_out.
    if (s != 0 && is14) Y[(s - 1) * BATCH + elem] = accB;

    hA = tanh_fast(accA);
    hB = tanh_fast(accB);
  };

  for (int s = 0; s < SEQ; s += 8) {
    PIN_ALL()   // re-pin every 8 steps: spilling has no payoff anywhere
    STEP(s + 0, x0);
    STEP(s + 1, x1);
    STEP(s + 2, x2);
    STEP(s + 3, x3);
    STEP(s + 4, x4);
    STEP(s + 5, x5);
    STEP(s + 6, x6);
    STEP(s + 7, x7);
  }

  // Epilogue: y_{SEQ-1} from h_{SEQ-1} (hi/y chain only).
  {
    float b0 = fmaf(wc[0], hA, bHi);
    float b1 = wd[0] * hB;
#define KROTY(T)                                                             \
    {                                                                        \
      const float ra = __int_as_float(__builtin_amdgcn_mov_dpp(              \
          __float_as_int(hA), 0x120 + T, 0xf, 0xf, false));                  \
      const float rb = __int_as_float(__builtin_amdgcn_mov_dpp(              \
          __float_as_int(hB), 0x120 + T, 0xf, 0xf, false));                  \
      b0 = fmaf(wc[T], ra, b0);                                              \
      b1 = fmaf(wd[T], rb, b1);                                              \
    }
    KROTY(1)  KROTY(2)  KROTY(3)  KROTY(4)  KROTY(5)
    KROTY(6)  KROTY(7)  KROTY(8)  KROTY(9)  KROTY(10)
    KROTY(11) KROTY(12) KROTY(13) KROTY(14) KROTY(15)
    if (is14) Y[(SEQ - 1) * BATCH + elem] = b0 + b1;
  }
}

extern "C" void kernel_launch(void* const* d_in, const int* in_sizes, int n_in,
                              void* d_out, int out_size, void* d_ws, size_t ws_size,
                              hipStream_t stream) {
  const float* X     = (const float*)d_in[0];
  const float* W_ih  = (const float*)d_in[1];
  const float* W_hh  = (const float*)d_in[2];
  const float* b_ih  = (const float*)d_in[3];
  const float* b_hh  = (const float*)d_in[4];
  const float* W_out = (const float*)d_in[5];
  const float* b_out = (const float*)d_in[6];
  float* Y = (float*)d_out;

  // 16 lanes/elem: 256 blocks x 256 threads = 1024 waves = 1 per SIMD,
  // exactly 1 block per CU.
  dim3 grid(BATCH / 16), block(256);
  rnn_tanh_kernel<<<grid, block, 0, stream>>>(X, W_ih, W_hh, b_ih, b_hh,
                                              W_out, b_out, Y);
}